// Round 2
// 2804.879 us; speedup vs baseline: 1.2251x; 1.2251x over previous
//
#include <hip/hip_runtime.h>

// Liquid NN: BATCH=64, SEQ=256, IN=512, HID=1024, 2 layers, tau=0.5.
// h0(t) = h0 + a0*2*(tanh(x_t@W0^T + b0 + h0@U0^T) - h0)
// h1(t) = h1 + a1*2*(tanh(h0(t)@W1^T + b1 + h1@U1^T) - h1)
// Output: h1(255) as f32 (64,1024).
//
// 32 worker WGs elected onto ONE XCD (R4-validated election + FETCH collapse).
// Sync primitives are R4-validated AGENT atomics only (no inline-asm memory ops):
//   - per-producer flag WORDS: flagXw[j] = steps completed by WG j, published by
//     a single AGENT relaxed atomic STORE (no RMW -> no 16-way line contention)
//   - dependency poll: 16-lane vector AGENT atomic load (one 64B line =
//     one round trip), ALWAYS followed by __syncthreads before any slab read
//     (R5's barrier-free wave-local polls failed correctness; reverted)
//   - l1_inv (L1-only) before h-ring slab reads; producer h stores are drained
//     by __syncthreads (vmcnt0) before the flag store
//   - lockstep protocol: role0 step s waits flag0w[*]>=s, flag1w[*]>=s-7;
//     role1 step t waits flag0w[*]>=t+1, flag1w[*]>=t  (depth-8 rings safe)
// role 0 (16 WGs): h0(s) = EMA(tanh(wx[s] + U0*h0(s-1)))
// role 1 (16 WGs): h1(t) = EMA(tanh(b1 + W1*h0(t) + U1*h1(t-1)))
//   R6: role1 is TWO-PHASE: poll flag0 -> bar -> W1*h0(t) slab -> poll flag1 ->
//   bar -> U1*h1(t-1) slab. h0(t) is ready up to 8 steps early (ring slack), so
//   the W1 slab and the flag0 poll come OFF the serial flag1 chain; ordering is
//   provably equivalent (each gemm behind a barrier behind its full 16-word
//   poll; the h1-store ring check flag1w[*]>=t still precedes the store).
// R6: wx loads are NON-TEMPORAL (no-allocate) so the 33MB stream does not evict
//   the 2MB h-rings from the elected XCD's 4MB L2 (WRITE_SIZE 67MB/dispatch
//   showed the h-rings thrashing to HBM; with 1 WG/CU there is no TLP to hide
//   the resulting L3/HBM-latency slab loads on the serial chain).
// R6: fast tanh (exp-based, ~6 insts vs ~25 for libm tanhf); epilogue is fully
//   latency-exposed at 1 WG/CU. |err| ~1e-7 vs 2e-2 threshold.
// Epilogue: XOR-swizzled LDS transpose (aligned(16) -> legal b128), each thread
// owns one batch row x 16 consecutive cols -> 2x b128 h stores, 2x b128 wx loads.

typedef _Float16 f16;
typedef _Float16 f16x8 __attribute__((ext_vector_type(8)));
typedef float    f32x4 __attribute__((ext_vector_type(4)));

#define B_  64
#define S_  256
#define IN_ 512
#define H_  1024

static constexpr size_t OFF_WX  = 0;         // S*B*H f16 = 33554432
static constexpr size_t OFF_H0R = 33554432;  // 8*B*H f16 = 1048576
static constexpr size_t OFF_H1R = 34603008;  // 8*B*H f16 = 1048576
static constexpr size_t OFF_FLG = 35651584;  // flags
// flg ints: flag0w[16]@0 (line 0), flag1w[16]@16 (line 1),
//           cnt[8]@32, chosen@40, ticket@41 (line 2)

#define AGENT __HIP_MEMORY_SCOPE_AGENT

// ---------------- kernel: Wx = x @ W0^T + b0 (f32 in, f16 out) ----------------
__global__ __launch_bounds__(256) void k_wx(const float* __restrict__ x,
                                            const float* __restrict__ W0,
                                            const float* __restrict__ b0,
                                            f16* __restrict__ wx) {
  __shared__ uint4 xs[4096];  // 64 rows x 64 8-half chunks, chunk' = kc ^ (row&7)
  const int tid = threadIdx.x;
  const int w = tid >> 6, lane = tid & 63;
  const int q = lane >> 4, l15 = lane & 15;
  const int cslice = blockIdx.x & 15;
  const int rblock = blockIdx.x >> 4;  // 0..31
  const int c = cslice * 64 + w * 16 + l15;

  f16x8 Bf[16];  // B[k][n] = W0[c][k], lane holds k = kf*32 + q*8 + j
#pragma unroll
  for (int kf = 0; kf < 16; ++kf) {
    const float* p = W0 + (size_t)c * IN_ + kf * 32 + q * 8;
    f16x8 v;
#pragma unroll
    for (int j = 0; j < 8; ++j) v[j] = (f16)p[j];
    Bf[kf] = v;
  }
  const float bias = b0[c];

  for (int rt = 0; rt < 8; ++rt) {
    const int row0 = rblock * 512 + rt * 64;
    __syncthreads();
#pragma unroll
    for (int it = 0; it < 16; ++it) {
      int g = it * 256 + tid;
      int r = g >> 6, kc = g & 63;
      const float* xp = x + (size_t)(row0 + r) * IN_ + kc * 8;
      float4 v0 = *(const float4*)xp;
      float4 v1 = *(const float4*)(xp + 4);
      f16x8 h;
      h[0] = (f16)v0.x; h[1] = (f16)v0.y; h[2] = (f16)v0.z; h[3] = (f16)v0.w;
      h[4] = (f16)v1.x; h[5] = (f16)v1.y; h[6] = (f16)v1.z; h[7] = (f16)v1.w;
      xs[r * 64 + (kc ^ (r & 7))] = *(uint4*)&h;
    }
    __syncthreads();
    f32x4 acc[4] = {};
#pragma unroll
    for (int mt = 0; mt < 4; ++mt) {
      const int r = mt * 16 + l15;
#pragma unroll
      for (int kf = 0; kf < 16; ++kf) {
        uint4 av = xs[r * 64 + ((kf * 4 + q) ^ (r & 7))];
        f16x8 a = *(f16x8*)&av;
        acc[mt] = __builtin_amdgcn_mfma_f32_16x16x32_f16(a, Bf[kf], acc[mt], 0, 0, 0);
      }
    }
#pragma unroll
    for (int mt = 0; mt < 4; ++mt) {
#pragma unroll
      for (int r = 0; r < 4; ++r) {
        int rowg = row0 + mt * 16 + q * 4 + r;  // = b*256 + t
        int b = rowg >> 8, t = rowg & 255;
        wx[((size_t)t * B_ + b) * H_ + c] = (f16)(acc[mt][r] + bias);
      }
    }
  }
}

// ---------------- persistent recurrent kernel ----------------
__device__ __forceinline__ void l1_inv() {
  asm volatile("buffer_inv" ::: "memory");  // L1-only: elected-XCD L2 is coherence pt
}

// whole-wave vector poll: lanes 0-15 wait f[lane] >= tgt (one 64B line / round trip)
__device__ __forceinline__ void pollw(const int* f, int tgt, int lane) {
  bool pend = (lane < 16) && (tgt > 0);
  const int* p = f + (lane & 15);
  while (__ballot(pend)) {
    if (pend && __hip_atomic_load((int*)p, __ATOMIC_RELAXED, AGENT) >= tgt)
      pend = false;
  }
}

// fast tanh: t = e^{-2|x|} in (0,1], tanh = sign(x)*(1-t)/(1+t). No overflow,
// ~1e-7 abs err, ~6 VALU ops vs ~25 for libm tanhf (which is fully exposed
// latency at 1 WG/CU).
__device__ __forceinline__ float fast_tanh(float x) {
  float t = __expf(-2.0f * fabsf(x));
  float r = (1.0f - t) / (1.0f + t);
  return copysignf(r, x);
}

// one wave: 64-batch x 64-col x 256-K slab, software-pipelined A loads.
__device__ __forceinline__ void gemm_slab(const f16* __restrict__ A, int kbase,
                                          int l15, int q,
                                          const f16x8 (&Bf)[4][8], f32x4 (&acc)[4][4]) {
  f16x8 cur[8], nxt[8];
  const f16* ar0 = A + (size_t)l15 * H_ + kbase + q * 8;
#pragma unroll
  for (int kf = 0; kf < 8; ++kf) cur[kf] = *(const f16x8*)(ar0 + kf * 32);
#pragma unroll
  for (int mt = 0; mt < 4; ++mt) {
    if (mt < 3) {
      const f16* ar = A + (size_t)((mt + 1) * 16 + l15) * H_ + kbase + q * 8;
#pragma unroll
      for (int kf = 0; kf < 8; ++kf) nxt[kf] = *(const f16x8*)(ar + kf * 32);
    }
#pragma unroll
    for (int nt = 0; nt < 4; ++nt)
#pragma unroll
      for (int kf = 0; kf < 8; ++kf)
        acc[mt][nt] = __builtin_amdgcn_mfma_f32_16x16x32_f16(cur[kf], Bf[nt][kf],
                                                             acc[mt][nt], 0, 0, 0);
#pragma unroll
    for (int kf = 0; kf < 8; ++kf) cur[kf] = nxt[kf];
  }
}

__global__ __launch_bounds__(256, 1) void k_persist(
    const float* __restrict__ U0, const float* __restrict__ W1,
    const float* __restrict__ U1, const float* __restrict__ alpha0,
    const float* __restrict__ alpha1, const float* __restrict__ b1,
    const f16* __restrict__ wx, f16* h0r, f16* h1r, int* flg, float* out) {
  // red[ks][i][col]: D[m][n] of K-slice ks, m=(i>>4)*16+(col>>4)*4+(i&3),
  // n=((i>>2)&3)*16+(col&15), stored XOR-swizzled at col' = col ^ ((i&3)<<2).
  // aligned(16): epilogue does b128 LDS reads (under-aligned b128 = fault).
  __shared__ __attribute__((aligned(16))) float red[4][64][64];  // exactly 64 KiB
  const int tid = threadIdx.x;
  const int w = tid >> 6, lane = tid & 63;
  const int q = lane >> 4, l15 = lane & 15;

  int* flag0w = flg;        // word j = steps completed by role0 WG j
  int* flag1w = flg + 16;   // word j = steps completed by role1 WG j
  int* cnt    = flg + 32;
  int* chosen = flg + 40;
  int* ticket = flg + 41;

  // ---- elect one XCD; 32 workers there; everyone else exits (R4-validated) ----
  const int xcc = (int)__builtin_amdgcn_s_getreg(6164) & 7;  // HW_REG_XCC_ID
  int* sh = (int*)&red[0][0][0];
  if (tid == 0) {
    __hip_atomic_fetch_add(cnt + xcc, 1, __ATOMIC_RELAXED, AGENT);
    if (blockIdx.x == 0) {
      int sel = -1;
      while (sel < 0) {
        for (int i = 0; i < 8; ++i)
          if (__hip_atomic_load(cnt + i, __ATOMIC_RELAXED, AGENT) >= 32) { sel = i; break; }
        if (sel < 0) __builtin_amdgcn_s_sleep(1);
      }
      __hip_atomic_fetch_add(chosen, sel + 1, __ATOMIC_RELAXED, AGENT);
    }
    int ch;
    while ((ch = __hip_atomic_load(chosen, __ATOMIC_RELAXED, AGENT)) == 0)
      __builtin_amdgcn_s_sleep(1);
    int my = -1;
    if (xcc == ch - 1) my = __hip_atomic_fetch_add(ticket, 1, __ATOMIC_RELAXED, AGENT);
    sh[0] = my;
  }
  __syncthreads();
  const int myid = sh[0];
  __syncthreads();
  if (myid < 0 || myid >= 32) return;
  const int role = myid >> 4, slice = myid & 15;
  const int c0 = slice * 64;
  const int kbase = w * 256;

  // ---- weight slices into registers: B[k][n] = Wm[c][k] ----
  f16x8 BfA[4][8];  // role0: U0 ; role1: W1
  f16x8 BfB[4][8];  // role1: U1
  {
    const float* WmA = (role == 0) ? U0 : W1;
#pragma unroll
    for (int nt = 0; nt < 4; ++nt)
#pragma unroll
      for (int kf = 0; kf < 8; ++kf) {
        const float* p = WmA + (size_t)(c0 + nt * 16 + l15) * H_ + kbase + kf * 32 + q * 8;
        f16x8 v;
#pragma unroll
        for (int j = 0; j < 8; ++j) v[j] = (f16)p[j];
        BfA[nt][kf] = v;
      }
    if (role == 1) {
#pragma unroll
      for (int nt = 0; nt < 4; ++nt)
#pragma unroll
        for (int kf = 0; kf < 8; ++kf) {
          const float* p = U1 + (size_t)(c0 + nt * 16 + l15) * H_ + kbase + kf * 32 + q * 8;
          f16x8 v;
#pragma unroll
          for (int j = 0; j < 8; ++j) v[j] = (f16)p[j];
          BfB[nt][kf] = v;
        }
    }
  }

  // ---- epilogue ownership: thread owns batch row bown, cols cbase..cbase+15 ----
  const int bown = w * 16 + (lane & 15);
  const int gq   = lane >> 4;
  const int iidx = w * 16 + gq * 4 + (lane & 3);  // fixed LDS row
  const int lsb  = ((lane >> 2) & 3) * 16;        // fixed logical col base
  const int swz  = (lane & 3) << 2;               // read-side XOR (row&3 == lane&3)
  const int cbase = c0 + gq * 16;

  f16x8 cfh[2], bsh[2];  // packed alpha*2 and bias for the 16 owned cols
  {
    const float* ap = ((role == 0) ? alpha0 : alpha1) + cbase;
    const float* bp = b1 + cbase;
    f16x8 t0, t1, u0, u1;
#pragma unroll
    for (int j = 0; j < 8; ++j) {
      t0[j] = (f16)(ap[j] * 2.0f);
      t1[j] = (f16)(ap[8 + j] * 2.0f);
      u0[j] = (f16)bp[j];
      u1[j] = (f16)bp[8 + j];
    }
    cfh[0] = t0; cfh[1] = t1; bsh[0] = u0; bsh[1] = u1;
  }

  float hst[16];
#pragma unroll
  for (int i = 0; i < 16; ++i) hst[i] = 0.f;

  if (role == 0) {
    for (int s = 0; s < 256; ++s) {
      // prefetch wx[s] for owned (b, cols): 2 x b128 NT loads (no L2 allocate ->
      // h-rings stay L2-resident), in flight during the poll
      const f16* wp = wx + ((size_t)s * B_ + bown) * H_ + cbase;
      f16x8 wxa = __builtin_nontemporal_load((const f16x8*)wp);
      f16x8 wxb = __builtin_nontemporal_load((const f16x8*)(wp + 8));
      f32x4 acc[4][4] = {};
      if (s > 0) {
        if (w == 0) pollw(flag0w, s, lane);              // peers finished s-1
        if (w == 1) pollw(flag1w, s - 7, lane);          // ring slot s&7 free
        __syncthreads();
        l1_inv();
        gemm_slab(h0r + (size_t)((s - 1) & 7) * B_ * H_, kbase, l15, q, BfA, acc);
      }
#pragma unroll
      for (int mt = 0; mt < 4; ++mt)
#pragma unroll
        for (int nt = 0; nt < 4; ++nt)
#pragma unroll
          for (int r = 0; r < 4; ++r)
            red[w][mt * 16 + nt * 4 + r][lane ^ (r << 2)] = acc[mt][nt][r];
      __syncthreads();
      float vs[16];
#pragma unroll
      for (int ks = 0; ks < 4; ++ks)
#pragma unroll
        for (int ch = 0; ch < 4; ++ch) {
          f32x4 v = *(const f32x4*)&red[ks][iidx][lsb + ((ch << 2) ^ swz)];
          if (ks == 0) {
            vs[ch*4+0] = v[0]; vs[ch*4+1] = v[1]; vs[ch*4+2] = v[2]; vs[ch*4+3] = v[3];
          } else {
            vs[ch*4+0] += v[0]; vs[ch*4+1] += v[1]; vs[ch*4+2] += v[2]; vs[ch*4+3] += v[3];
          }
        }
      f16* hw = h0r + (size_t)(s & 7) * B_ * H_ + (size_t)bown * H_ + cbase;
      f16x8 o0, o1;
#pragma unroll
      for (int j = 0; j < 16; ++j) {
        float wxv = (float)((j < 8) ? wxa[j] : wxb[j - 8]);
        float cf  = (float)((j < 8) ? cfh[0][j] : cfh[1][j - 8]);
        float th = fast_tanh(vs[j] + wxv);
        float h = hst[j];
        h = h + cf * (th - h);
        hst[j] = h;
        if (j < 8) o0[j] = (f16)h; else o1[j - 8] = (f16)h;
      }
      *(f16x8*)hw = o0;
      *(f16x8*)(hw + 8) = o1;
      __syncthreads();  // vmcnt(0) per wave: h stores in shared L2 before flag
      if (tid == 0)
        __hip_atomic_store(flag0w + slice, s + 1, __ATOMIC_RELAXED, AGENT);
    }
  } else {
    for (int t = 0; t < 256; ++t) {
      f32x4 acc[4][4] = {};
      // phase A: W1*h0(t). h0 is ready up to 8 steps early (ring slack), so this
      // poll is normally instant and the slab comes OFF the serial flag1 chain.
      if (w == 0) pollw(flag0w, t + 1, lane);            // h0(t) ready
      __syncthreads();
      l1_inv();
      gemm_slab(h0r + (size_t)(t & 7) * B_ * H_, kbase, l15, q, BfA, acc);  // W1*h0(t)
      if (t > 0) {
        // phase B: U1*h1(t-1). flag1w[*]>=t covers peers' h1(t-1) AND the ring
        // (slot t&7 free) -- checked before the h1 store below via this barrier.
        if (w == 0) pollw(flag1w, t, lane);
        __syncthreads();
        l1_inv();
        gemm_slab(h1r + (size_t)((t - 1) & 7) * B_ * H_, kbase, l15, q, BfB, acc);
      }
#pragma unroll
      for (int mt = 0; mt < 4; ++mt)
#pragma unroll
        for (int nt = 0; nt < 4; ++nt)
#pragma unroll
          for (int r = 0; r < 4; ++r)
            red[w][mt * 16 + nt * 4 + r][lane ^ (r << 2)] = acc[mt][nt][r];
      __syncthreads();
      float vs[16];
#pragma unroll
      for (int ks = 0; ks < 4; ++ks)
#pragma unroll
        for (int ch = 0; ch < 4; ++ch) {
          f32x4 v = *(const f32x4*)&red[ks][iidx][lsb + ((ch << 2) ^ swz)];
          if (ks == 0) {
            vs[ch*4+0] = v[0]; vs[ch*4+1] = v[1]; vs[ch*4+2] = v[2]; vs[ch*4+3] = v[3];
          } else {
            vs[ch*4+0] += v[0]; vs[ch*4+1] += v[1]; vs[ch*4+2] += v[2]; vs[ch*4+3] += v[3];
          }
        }
      f16* hw = h1r + (size_t)(t & 7) * B_ * H_ + (size_t)bown * H_ + cbase;
      f16x8 o0, o1;
#pragma unroll
      for (int j = 0; j < 16; ++j) {
        float bs = (float)((j < 8) ? bsh[0][j] : bsh[1][j - 8]);
        float cf = (float)((j < 8) ? cfh[0][j] : cfh[1][j - 8]);
        float th = fast_tanh(vs[j] + bs);
        float h = hst[j];
        h = h + cf * (th - h);
        hst[j] = h;
        if (j < 8) o0[j] = (f16)h; else o1[j - 8] = (f16)h;
      }
      *(f16x8*)hw = o0;
      *(f16x8*)(hw + 8) = o1;
      if (t == 255) {
        float* op = out + (size_t)bown * H_ + cbase;
#pragma unroll
        for (int ch = 0; ch < 4; ++ch) {
          float4 vv;
          vv.x = hst[ch*4+0]; vv.y = hst[ch*4+1]; vv.z = hst[ch*4+2]; vv.w = hst[ch*4+3];
          *(float4*)(op + ch * 4) = vv;
        }
      }
      __syncthreads();
      if (tid == 0)
        __hip_atomic_store(flag1w + slice, t + 1, __ATOMIC_RELAXED, AGENT);
    }
  }
}

// Swizzle identity: writer lane L stores logical col L at physical col
// L ^ ((i&3)<<2). Reader (row iidx, iidx&3 == lane&3) reads physical
// lsb + ((ch<<2) ^ ((lane&3)<<2)) + nn, which un-XORs to logical
// lsb + ch*4 + nn. Writes are lane-permutations (conflict-free); b128 reads
// spread across all 32 banks (conflict-free).

extern "C" void kernel_launch(void* const* d_in, const int* in_sizes, int n_in,
                              void* d_out, int out_size, void* d_ws, size_t ws_size,
                              hipStream_t stream) {
  const float* x  = (const float*)d_in[0];
  const float* W0 = (const float*)d_in[1];
  const float* U0 = (const float*)d_in[2];
  const float* b0 = (const float*)d_in[3];
  const float* a0 = (const float*)d_in[4];
  const float* W1 = (const float*)d_in[5];
  const float* U1 = (const float*)d_in[6];
  const float* b1 = (const float*)d_in[7];
  const float* a1 = (const float*)d_in[8];
  char* ws = (char*)d_ws;
  f16*   wx  = (f16*)(ws + OFF_WX);
  f16*   h0r = (f16*)(ws + OFF_H0R);
  f16*   h1r = (f16*)(ws + OFF_H1R);
  int*   flg = (int*)(ws + OFF_FLG);
  float* out = (float*)d_out;

  hipMemsetAsync(flg, 0, 8192, stream);            // flags/election start at 0
  k_wx<<<512, 256, 0, stream>>>(x, W0, b0, wx);    // parallel Wx GEMM

  // 256 blocks: every XCD gets >=32 by pigeonhole; workers self-select onto one.
  k_persist<<<256, 256, 0, stream>>>(U0, W1, U1, a0, a1, b1, wx, h0r, h1r, flg, out);
}